// Round 2
// baseline (1068.810 us; speedup 1.0000x reference)
//
#include <hip/hip_runtime.h>

#define EMB 64
#define CHUNK 512   // edges per wave

// SUM = emb (f32 copy), vectorized
__global__ void __launch_bounds__(256) k_copy(const float* __restrict__ emb,
                                              float* __restrict__ sum, int n) {
    int idx = (blockIdx.x * blockDim.x + threadIdx.x) * 4;
    if (idx >= n) return;
    *reinterpret_cast<float4*>(sum + idx) =
        *reinterpret_cast<const float4*>(emb + idx);
}

// Segmented SpMM: Y[row[e]][lane] += vals[e] * X[col[e]][lane]
// One wave handles CHUNK consecutive edges; rows are sorted ascending.
__global__ void __launch_bounds__(256) k_spmm(const int* __restrict__ row,
                                              const int* __restrict__ col,
                                              const float* __restrict__ vals,
                                              const float* __restrict__ X,
                                              float* __restrict__ Y, int nEdges) {
    int wid  = (blockIdx.x * blockDim.x + threadIdx.x) >> 6;
    int lane = threadIdx.x & 63;
    int e0 = wid * CHUNK;
    if (e0 >= nEdges) return;
    int e1 = min(nEdges, e0 + CHUNK);

    int cur = row[e0];          // wave-uniform
    float acc = 0.f;
    bool first = true;

    for (int base = e0; base < e1; base += 64) {
        int n = min(64, e1 - base);
        int r = 0, c = 0; float v = 0.f;
        if (lane < n) {
            r = row[base + lane];
            c = col[base + lane];
            v = vals[base + lane];
        }
        if (n == 64) {
            #pragma unroll
            for (int j = 0; j < 64; ++j) {
                int   rj = __shfl(r, j);
                int   cj = __shfl(c, j);
                float vj = __shfl(v, j);
                if (rj != cur) {
                    float* dst = Y + cur * EMB + lane;
                    if (first) atomicAdd(dst, acc); else *dst = acc;
                    first = false; acc = 0.f; cur = rj;
                }
                acc = fmaf(vj, X[cj * EMB + lane], acc);
            }
        } else {
            for (int j = 0; j < n; ++j) {
                int   rj = __shfl(r, j);
                int   cj = __shfl(c, j);
                float vj = __shfl(v, j);
                if (rj != cur) {
                    float* dst = Y + cur * EMB + lane;
                    if (first) atomicAdd(dst, acc); else *dst = acc;
                    first = false; acc = 0.f; cur = rj;
                }
                acc = fmaf(vj, X[cj * EMB + lane], acc);
            }
        }
    }
    // last segment may continue into the next chunk -> atomic
    atomicAdd(Y + cur * EMB + lane, acc);
}

// SUM += Y
__global__ void __launch_bounds__(256) k_add(const float* __restrict__ Y,
                                             float* __restrict__ sum, int n) {
    int idx = (blockIdx.x * blockDim.x + threadIdx.x) * 4;
    if (idx >= n) return;
    float4 y = *reinterpret_cast<const float4*>(Y + idx);
    float4 s = *reinterpret_cast<const float4*>(sum + idx);
    s.x += y.x; s.y += y.y; s.z += y.z; s.w += y.w;
    *reinterpret_cast<float4*>(sum + idx) = s;
}

// SUM = (SUM + Y) * 0.25
__global__ void __launch_bounds__(256) k_final(const float* __restrict__ Y,
                                               float* __restrict__ sum, int n) {
    int idx = (blockIdx.x * blockDim.x + threadIdx.x) * 4;
    if (idx >= n) return;
    float4 y = *reinterpret_cast<const float4*>(Y + idx);
    float4 s = *reinterpret_cast<const float4*>(sum + idx);
    s.x = (s.x + y.x) * 0.25f;
    s.y = (s.y + y.y) * 0.25f;
    s.z = (s.z + y.z) * 0.25f;
    s.w = (s.w + y.w) * 0.25f;
    *reinterpret_cast<float4*>(sum + idx) = s;
}

extern "C" void kernel_launch(void* const* d_in, const int* in_sizes, int n_in,
                              void* d_out, int out_size, void* d_ws, size_t ws_size,
                              hipStream_t stream) {
    const float* emb  = (const float*)d_in[0];
    const int*   row  = (const int*)d_in[1];
    const int*   col  = (const int*)d_in[2];
    const float* vals = (const float*)d_in[3];

    int nemb = in_sizes[0];   // n_nodes * 64 = 9,600,000
    int E    = in_sizes[1];   // 4,800,000

    // ws layout: A f32 | B f32  (76.8 MB); SUM accumulates in d_out (f32)
    float* A   = (float*)d_ws;
    float* B   = A + nemb;
    float* SUM = (float*)d_out;

    dim3 blk(256);
    int gridE = (nemb / 4 + 255) / 256;

    int waves      = (E + CHUNK - 1) / CHUNK;
    int spmmBlocks = (waves + 3) / 4;

    k_copy<<<gridE, blk, 0, stream>>>(emb, SUM, nemb);

    // layer 0: emb -> A
    hipMemsetAsync(A, 0, (size_t)nemb * sizeof(float), stream);
    k_spmm<<<spmmBlocks, blk, 0, stream>>>(row, col, vals, emb, A, E);
    k_add<<<gridE, blk, 0, stream>>>(A, SUM, nemb);

    // layer 1: A -> B
    hipMemsetAsync(B, 0, (size_t)nemb * sizeof(float), stream);
    k_spmm<<<spmmBlocks, blk, 0, stream>>>(row, col, vals, A, B, E);
    k_add<<<gridE, blk, 0, stream>>>(B, SUM, nemb);

    // layer 2: B -> A (A's contents already folded into SUM)
    hipMemsetAsync(A, 0, (size_t)nemb * sizeof(float), stream);
    k_spmm<<<spmmBlocks, blk, 0, stream>>>(row, col, vals, B, A, E);
    k_final<<<gridE, blk, 0, stream>>>(A, SUM, nemb);
}

// Round 3
// 562.960 us; speedup vs baseline: 1.8986x; 1.8986x over previous
//
#include <hip/hip_runtime.h>

#define EMB 64

// Build CSR row pointers from the sorted row array.
// ptr[q] = first edge index e with row[e] >= q ; ptr[R] = E.
__global__ void __launch_bounds__(256) k_rowptr(const int* __restrict__ row,
                                                int* __restrict__ ptr, int E, int R) {
    int e = blockIdx.x * blockDim.x + threadIdx.x;
    if (e >= E) return;
    int r = row[e];
    int prev = (e == 0) ? -1 : row[e - 1];
    for (int q = prev + 1; q <= r; ++q) ptr[q] = e;
    if (e == E - 1) {
        for (int q = r + 1; q <= R; ++q) ptr[q] = E;
    }
}

// SUM = emb (f32 copy), vectorized
__global__ void __launch_bounds__(256) k_copy(const float* __restrict__ emb,
                                              float* __restrict__ sum, int n) {
    int idx = (blockIdx.x * blockDim.x + threadIdx.x) * 4;
    if (idx >= n) return;
    *reinterpret_cast<float4*>(sum + idx) =
        *reinterpret_cast<const float4*>(emb + idx);
}

// CSR SpMM, one 16-lane group per row; lane owns 4 dims (float4).
//   acc = sum_e vals[e] * X[col[e]]      (row's edge range from ptr)
//   FINAL=0:  Y[row] = acc; SUM[row] += acc
//   FINAL=1:  SUM[row] = (SUM[row] + acc) * 0.25
template <int FINAL>
__global__ void __launch_bounds__(256) k_spmm(const int* __restrict__ ptr,
                                              const int* __restrict__ col,
                                              const float* __restrict__ vals,
                                              const float* __restrict__ X,
                                              float* __restrict__ Y,
                                              float* __restrict__ SUM, int R) {
    int tid = blockIdx.x * blockDim.x + threadIdx.x;
    int g   = tid >> 4;        // row id
    int gl  = tid & 15;        // lane within group: dims [4*gl, 4*gl+4)
    if (g >= R) return;

    int s = ptr[g];
    int e = ptr[g + 1];

    float4 acc = make_float4(0.f, 0.f, 0.f, 0.f);

    for (int base = s; base < e; base += 16) {
        int n = min(16, e - base);
        int   c = 0;
        float v = 0.f;
        if (gl < n) {
            c = col[base + gl];
            v = vals[base + gl];
        }
        if (n == 16) {
            // phase 1: broadcast cols, issue all 16 gathers
            float4 xv[16];
            float  vj[16];
            #pragma unroll
            for (int j = 0; j < 16; ++j) {
                int cj = __shfl(c, j, 16);
                vj[j]  = __shfl(v, j, 16);
                xv[j]  = *reinterpret_cast<const float4*>(X + cj * EMB + gl * 4);
            }
            // phase 2: accumulate
            #pragma unroll
            for (int j = 0; j < 16; ++j) {
                acc.x = fmaf(vj[j], xv[j].x, acc.x);
                acc.y = fmaf(vj[j], xv[j].y, acc.y);
                acc.z = fmaf(vj[j], xv[j].z, acc.z);
                acc.w = fmaf(vj[j], xv[j].w, acc.w);
            }
        } else {
            for (int j = 0; j < n; ++j) {
                int   cj = __shfl(c, j, 16);
                float vjs = __shfl(v, j, 16);
                float4 xv = *reinterpret_cast<const float4*>(X + cj * EMB + gl * 4);
                acc.x = fmaf(vjs, xv.x, acc.x);
                acc.y = fmaf(vjs, xv.y, acc.y);
                acc.z = fmaf(vjs, xv.z, acc.z);
                acc.w = fmaf(vjs, xv.w, acc.w);
            }
        }
    }

    float4* srow = reinterpret_cast<float4*>(SUM + g * EMB + gl * 4);
    float4  sv   = *srow;
    if (FINAL) {
        sv.x = (sv.x + acc.x) * 0.25f;
        sv.y = (sv.y + acc.y) * 0.25f;
        sv.z = (sv.z + acc.z) * 0.25f;
        sv.w = (sv.w + acc.w) * 0.25f;
        *srow = sv;
    } else {
        sv.x += acc.x; sv.y += acc.y; sv.z += acc.z; sv.w += acc.w;
        *srow = sv;
        *reinterpret_cast<float4*>(Y + g * EMB + gl * 4) = acc;
    }
}

extern "C" void kernel_launch(void* const* d_in, const int* in_sizes, int n_in,
                              void* d_out, int out_size, void* d_ws, size_t ws_size,
                              hipStream_t stream) {
    const float* emb  = (const float*)d_in[0];
    const int*   row  = (const int*)d_in[1];
    const int*   col  = (const int*)d_in[2];
    const float* vals = (const float*)d_in[3];

    int nemb = in_sizes[0];   // n_nodes * 64 = 9,600,000
    int E    = in_sizes[1];   // 4,800,000
    int R    = nemb / EMB;    // 150,000

    // ws layout: A f32 | B f32 | ptr int   (≈ 77.4 MB)
    float* A   = (float*)d_ws;
    float* B   = A + nemb;
    int*   ptr = (int*)(B + nemb);
    float* SUM = (float*)d_out;

    dim3 blk(256);
    int gridE    = (E + 255) / 256;
    int gridCopy = (nemb / 4 + 255) / 256;
    int gridRows = (R * 16 + 255) / 256;

    k_rowptr<<<gridE, blk, 0, stream>>>(row, ptr, E, R);
    k_copy<<<gridCopy, blk, 0, stream>>>(emb, SUM, nemb);

    // layer 0: emb -> A, SUM += A
    k_spmm<0><<<gridRows, blk, 0, stream>>>(ptr, col, vals, emb, A, SUM, R);
    // layer 1: A -> B, SUM += B
    k_spmm<0><<<gridRows, blk, 0, stream>>>(ptr, col, vals, A, B, SUM, R);
    // layer 2: B -> (discard), SUM = (SUM + acc) * 0.25
    k_spmm<1><<<gridRows, blk, 0, stream>>>(ptr, col, vals, B, A, SUM, R);
}

// Round 4
// 344.215 us; speedup vs baseline: 3.1051x; 1.6355x over previous
//
#include <hip/hip_runtime.h>

#define EMB 64

// --- bf16 helpers (RNE) ---
__device__ __forceinline__ float bl(unsigned int u) { return __uint_as_float(u << 16); }
__device__ __forceinline__ float bh(unsigned int u) { return __uint_as_float(u & 0xffff0000u); }
__device__ __forceinline__ unsigned int pack2(float a, float b) {
    unsigned int ua = __float_as_uint(a); ua += 0x7fffu + ((ua >> 16) & 1u);
    unsigned int ub = __float_as_uint(b); ub += 0x7fffu + ((ub >> 16) & 1u);
    return (ua >> 16) | (ub & 0xffff0000u);
}

// Build CSR row pointers from the sorted row array.
__global__ void __launch_bounds__(256) k_rowptr(const int* __restrict__ row,
                                                int* __restrict__ ptr, int E, int R) {
    int e = blockIdx.x * blockDim.x + threadIdx.x;
    if (e >= E) return;
    int r = row[e];
    int prev = (e == 0) ? -1 : row[e - 1];
    for (int q = prev + 1; q <= r; ++q) ptr[q] = e;
    if (e == E - 1) {
        for (int q = r + 1; q <= R; ++q) ptr[q] = E;
    }
}

// SUM = emb (f32), X0 = bf16(emb). One thread handles 8 elems.
__global__ void __launch_bounds__(256) k_prep(const float* __restrict__ emb,
                                              float* __restrict__ sum,
                                              uint4* __restrict__ Xb, int n8) {
    int i = blockIdx.x * blockDim.x + threadIdx.x;
    if (i >= n8) return;
    const float4* p = reinterpret_cast<const float4*>(emb) + (size_t)i * 2;
    float4 a = p[0], b = p[1];
    float4* sp = reinterpret_cast<float4*>(sum) + (size_t)i * 2;
    sp[0] = a; sp[1] = b;
    uint4 x;
    x.x = pack2(a.x, a.y); x.y = pack2(a.z, a.w);
    x.z = pack2(b.x, b.y); x.w = pack2(b.z, b.w);
    Xb[i] = x;
}

// CSR SpMM, one 8-lane group per row; lane owns 8 dims (one uint4 = 8 bf16).
//   acc = sum_e vals[e] * X[col[e]]
//   FINAL=0:  Yb[row] = bf16(acc); SUM[row] += acc
//   FINAL=1:  SUM[row] = (SUM[row] + acc) * 0.25
template <int FINAL>
__global__ void __launch_bounds__(256) k_spmm(const int* __restrict__ ptr,
                                              const int* __restrict__ col,
                                              const float* __restrict__ vals,
                                              const uint4* __restrict__ Xb,
                                              uint4* __restrict__ Yb,
                                              float* __restrict__ SUM, int R) {
    int tid = blockIdx.x * blockDim.x + threadIdx.x;
    int g   = tid >> 3;       // row id
    int gl  = tid & 7;        // lane in group: dims [8*gl, 8*gl+8)
    if (g >= R) return;

    int s = ptr[g];
    int e = ptr[g + 1];

    float acc0 = 0.f, acc1 = 0.f, acc2 = 0.f, acc3 = 0.f;
    float acc4 = 0.f, acc5 = 0.f, acc6 = 0.f, acc7 = 0.f;

    for (int base = s; base < e; base += 8) {
        int n = min(8, e - base);
        int   c = 0;
        float v = 0.f;
        if (gl < n) {
            c = col[base + gl];
            v = vals[base + gl];
        }
        if (n == 8) {
            int   cj[8];
            float vj[8];
            #pragma unroll
            for (int j = 0; j < 8; ++j) {
                cj[j] = __shfl(c, j, 8);
                vj[j] = __shfl(v, j, 8);
            }
            uint4 xv[8];
            #pragma unroll
            for (int j = 0; j < 8; ++j)
                xv[j] = Xb[(size_t)cj[j] * 8 + gl];
            #pragma unroll
            for (int j = 0; j < 8; ++j) {
                acc0 = fmaf(vj[j], bl(xv[j].x), acc0);
                acc1 = fmaf(vj[j], bh(xv[j].x), acc1);
                acc2 = fmaf(vj[j], bl(xv[j].y), acc2);
                acc3 = fmaf(vj[j], bh(xv[j].y), acc3);
                acc4 = fmaf(vj[j], bl(xv[j].z), acc4);
                acc5 = fmaf(vj[j], bh(xv[j].z), acc5);
                acc6 = fmaf(vj[j], bl(xv[j].w), acc6);
                acc7 = fmaf(vj[j], bh(xv[j].w), acc7);
            }
        } else {
            for (int j = 0; j < n; ++j) {
                int   cjj = __shfl(c, j, 8);
                float vjs = __shfl(v, j, 8);
                uint4 xv  = Xb[(size_t)cjj * 8 + gl];
                acc0 = fmaf(vjs, bl(xv.x), acc0);
                acc1 = fmaf(vjs, bh(xv.x), acc1);
                acc2 = fmaf(vjs, bl(xv.y), acc2);
                acc3 = fmaf(vjs, bh(xv.y), acc3);
                acc4 = fmaf(vjs, bl(xv.z), acc4);
                acc5 = fmaf(vjs, bh(xv.z), acc5);
                acc6 = fmaf(vjs, bl(xv.w), acc6);
                acc7 = fmaf(vjs, bh(xv.w), acc7);
            }
        }
    }

    float4* sp = reinterpret_cast<float4*>(SUM + (size_t)g * EMB + gl * 8);
    float4 a = sp[0], b = sp[1];
    if (FINAL) {
        a.x = (a.x + acc0) * 0.25f; a.y = (a.y + acc1) * 0.25f;
        a.z = (a.z + acc2) * 0.25f; a.w = (a.w + acc3) * 0.25f;
        b.x = (b.x + acc4) * 0.25f; b.y = (b.y + acc5) * 0.25f;
        b.z = (b.z + acc6) * 0.25f; b.w = (b.w + acc7) * 0.25f;
        sp[0] = a; sp[1] = b;
    } else {
        a.x += acc0; a.y += acc1; a.z += acc2; a.w += acc3;
        b.x += acc4; b.y += acc5; b.z += acc6; b.w += acc7;
        sp[0] = a; sp[1] = b;
        uint4 y;
        y.x = pack2(acc0, acc1); y.y = pack2(acc2, acc3);
        y.z = pack2(acc4, acc5); y.w = pack2(acc6, acc7);
        Yb[(size_t)g * 8 + gl] = y;
    }
}

extern "C" void kernel_launch(void* const* d_in, const int* in_sizes, int n_in,
                              void* d_out, int out_size, void* d_ws, size_t ws_size,
                              hipStream_t stream) {
    const float* emb  = (const float*)d_in[0];
    const int*   row  = (const int*)d_in[1];
    const int*   col  = (const int*)d_in[2];
    const float* vals = (const float*)d_in[3];

    int nemb = in_sizes[0];   // n_nodes * 64 = 9,600,000
    int E    = in_sizes[1];   // 4,800,000
    int R    = nemb / EMB;    // 150,000

    // ws layout: X0 bf16 | X1 bf16 | ptr int  (≈ 39 MB)
    uint4* X0  = (uint4*)d_ws;                 // nemb/8 uint4
    uint4* X1  = X0 + nemb / 8;
    int*   ptr = (int*)(X1 + nemb / 8);
    float* SUM = (float*)d_out;

    dim3 blk(256);
    int gridE    = (E + 255) / 256;
    int gridPrep = (nemb / 8 + 255) / 256;
    int gridRows = (R * 8 + 255) / 256;

    k_rowptr<<<gridE, blk, 0, stream>>>(row, ptr, E, R);
    k_prep<<<gridPrep, blk, 0, stream>>>(emb, SUM, X0, nemb / 8);

    // layer 0: X0 -> X1, SUM += acc
    k_spmm<0><<<gridRows, blk, 0, stream>>>(ptr, col, vals, X0, X1, SUM, R);
    // layer 1: X1 -> X0, SUM += acc
    k_spmm<0><<<gridRows, blk, 0, stream>>>(ptr, col, vals, X1, X0, SUM, R);
    // layer 2: X0 -> (none), SUM = (SUM + acc) * 0.25
    k_spmm<1><<<gridRows, blk, 0, stream>>>(ptr, col, vals, X0, X1, SUM, R);
}

// Round 5
// 280.716 us; speedup vs baseline: 3.8074x; 1.2262x over previous
//
#include <hip/hip_runtime.h>

#define EMB 64

// --- bf16 helpers (RNE) ---
__device__ __forceinline__ float bl(unsigned int u) { return __uint_as_float(u << 16); }
__device__ __forceinline__ float bh(unsigned int u) { return __uint_as_float(u & 0xffff0000u); }
__device__ __forceinline__ unsigned int pack2(float a, float b) {
    unsigned int ua = __float_as_uint(a); ua += 0x7fffu + ((ua >> 16) & 1u);
    unsigned int ub = __float_as_uint(b); ub += 0x7fffu + ((ub >> 16) & 1u);
    return (ua >> 16) | (ub & 0xffff0000u);
}

// Build CSR row pointers from the sorted row array.
__global__ void __launch_bounds__(256) k_rowptr(const int* __restrict__ row,
                                                int* __restrict__ ptr, int E, int R) {
    int e = blockIdx.x * blockDim.x + threadIdx.x;
    if (e >= E) return;
    int r = row[e];
    int prev = (e == 0) ? -1 : row[e - 1];
    for (int q = prev + 1; q <= r; ++q) ptr[q] = e;
    if (e == E - 1) {
        for (int q = r + 1; q <= R; ++q) ptr[q] = E;
    }
}

// X0 = bf16(emb). One thread handles 8 elems.
__global__ void __launch_bounds__(256) k_prep(const float* __restrict__ emb,
                                              uint4* __restrict__ Xb, int n8) {
    int i = blockIdx.x * blockDim.x + threadIdx.x;
    if (i >= n8) return;
    const float4* p = reinterpret_cast<const float4*>(emb) + (size_t)i * 2;
    float4 a = p[0], b = p[1];
    uint4 x;
    x.x = pack2(a.x, a.y); x.y = pack2(a.z, a.w);
    x.z = pack2(b.x, b.y); x.w = pack2(b.z, b.w);
    Xb[i] = x;
}

__device__ __forceinline__ void loadcv(const int* __restrict__ col,
                                       const float* __restrict__ vals,
                                       int idx, int lim, int& c, float& v) {
    int i = idx < lim ? idx : lim - 1;
    c = col[i];
    v = (idx < lim) ? vals[i] : 0.f;
}

// Pure CSR SpMM: Yb[row] = bf16( sum_e vals[e] * Xb[col[e]] )
// One 8-lane group per row; lane owns 8 dims (one uint4 = 8 bf16).
// 16-edge batches, gathers issued before FMA, next batch col/vals prefetched.
__global__ void __launch_bounds__(256) k_spmm(const int* __restrict__ ptr,
                                              const int* __restrict__ col,
                                              const float* __restrict__ vals,
                                              const uint4* __restrict__ Xb,
                                              uint4* __restrict__ Yb, int R) {
    int tid = blockIdx.x * blockDim.x + threadIdx.x;
    int g   = tid >> 3;       // row id
    int gl  = tid & 7;        // lane in group: dims [8*gl, 8*gl+8)
    if (g >= R) return;

    int s = ptr[g];
    int e = ptr[g + 1];

    if (s >= e) {             // empty row
        Yb[(size_t)g * 8 + gl] = make_uint4(0u, 0u, 0u, 0u);
        return;
    }

    float acc0 = 0.f, acc1 = 0.f, acc2 = 0.f, acc3 = 0.f;
    float acc4 = 0.f, acc5 = 0.f, acc6 = 0.f, acc7 = 0.f;

    int   c0, c1;
    float v0, v1;
    loadcv(col, vals, s + gl,     e, c0, v0);
    loadcv(col, vals, s + 8 + gl, e, c1, v1);

    for (int base = s; base < e; base += 16) {
        // broadcast 16 edges across the 8-lane group
        int   cj[16];
        float vj[16];
        #pragma unroll
        for (int j = 0; j < 8; ++j) {
            cj[j]     = __shfl(c0, j, 8);
            vj[j]     = __shfl(v0, j, 8);
            cj[8 + j] = __shfl(c1, j, 8);
            vj[8 + j] = __shfl(v1, j, 8);
        }
        // issue all 16 gathers
        uint4 xv[16];
        #pragma unroll
        for (int j = 0; j < 16; ++j)
            xv[j] = Xb[(size_t)cj[j] * 8 + gl];
        // prefetch next batch's edge data while gathers are in flight
        int nbase = base + 16;
        if (nbase < e) {
            loadcv(col, vals, nbase + gl,     e, c0, v0);
            loadcv(col, vals, nbase + 8 + gl, e, c1, v1);
        }
        // accumulate
        #pragma unroll
        for (int j = 0; j < 16; ++j) {
            acc0 = fmaf(vj[j], bl(xv[j].x), acc0);
            acc1 = fmaf(vj[j], bh(xv[j].x), acc1);
            acc2 = fmaf(vj[j], bl(xv[j].y), acc2);
            acc3 = fmaf(vj[j], bh(xv[j].y), acc3);
            acc4 = fmaf(vj[j], bl(xv[j].z), acc4);
            acc5 = fmaf(vj[j], bh(xv[j].z), acc5);
            acc6 = fmaf(vj[j], bl(xv[j].w), acc6);
            acc7 = fmaf(vj[j], bh(xv[j].w), acc7);
        }
    }

    uint4 y;
    y.x = pack2(acc0, acc1); y.y = pack2(acc2, acc3);
    y.z = pack2(acc4, acc5); y.w = pack2(acc6, acc7);
    Yb[(size_t)g * 8 + gl] = y;
}

// out = 0.25 * (emb + X1 + X2 + X3)
__global__ void __launch_bounds__(256) k_final(const float* __restrict__ emb,
                                               const uint4* __restrict__ X1,
                                               const uint4* __restrict__ X2,
                                               const uint4* __restrict__ X3,
                                               float* __restrict__ out, int n8) {
    int i = blockIdx.x * blockDim.x + threadIdx.x;
    if (i >= n8) return;
    const float4* p = reinterpret_cast<const float4*>(emb) + (size_t)i * 2;
    float4 a = p[0], b = p[1];
    uint4 x1 = X1[i], x2 = X2[i], x3 = X3[i];
    float4 o0, o1;
    o0.x = 0.25f * (a.x + bl(x1.x) + bl(x2.x) + bl(x3.x));
    o0.y = 0.25f * (a.y + bh(x1.x) + bh(x2.x) + bh(x3.x));
    o0.z = 0.25f * (a.z + bl(x1.y) + bl(x2.y) + bl(x3.y));
    o0.w = 0.25f * (a.w + bh(x1.y) + bh(x2.y) + bh(x3.y));
    o1.x = 0.25f * (b.x + bl(x1.z) + bl(x2.z) + bl(x3.z));
    o1.y = 0.25f * (b.y + bh(x1.z) + bh(x2.z) + bh(x3.z));
    o1.z = 0.25f * (b.z + bl(x1.w) + bl(x2.w) + bl(x3.w));
    o1.w = 0.25f * (b.w + bh(x1.w) + bh(x2.w) + bh(x3.w));
    float4* q = reinterpret_cast<float4*>(out) + (size_t)i * 2;
    q[0] = o0; q[1] = o1;
}

extern "C" void kernel_launch(void* const* d_in, const int* in_sizes, int n_in,
                              void* d_out, int out_size, void* d_ws, size_t ws_size,
                              hipStream_t stream) {
    const float* emb  = (const float*)d_in[0];
    const int*   row  = (const int*)d_in[1];
    const int*   col  = (const int*)d_in[2];
    const float* vals = (const float*)d_in[3];

    int nemb = in_sizes[0];   // n_nodes * 64 = 9,600,000
    int E    = in_sizes[1];   // 4,800,000
    int R    = nemb / EMB;    // 150,000

    // ws layout: X0|X1|X2|X3 bf16 (4 x 19.2 MB) | ptr int  (~77.4 MB)
    uint4* X0  = (uint4*)d_ws;                 // nemb/8 uint4 each
    uint4* X1  = X0 + nemb / 8;
    uint4* X2  = X1 + nemb / 8;
    uint4* X3  = X2 + nemb / 8;
    int*   ptr = (int*)(X3 + nemb / 8);

    dim3 blk(256);
    int gridE    = (E + 255) / 256;
    int gridElem = (nemb / 8 + 255) / 256;
    int gridRows = (R * 8 + 255) / 256;

    k_rowptr<<<gridE, blk, 0, stream>>>(row, ptr, E, R);
    k_prep<<<gridElem, blk, 0, stream>>>(emb, X0, nemb / 8);

    k_spmm<<<gridRows, blk, 0, stream>>>(ptr, col, vals, X0, X1, R);
    k_spmm<<<gridRows, blk, 0, stream>>>(ptr, col, vals, X1, X2, R);
    k_spmm<<<gridRows, blk, 0, stream>>>(ptr, col, vals, X2, X3, R);

    k_final<<<gridElem, blk, 0, stream>>>(emb, X1, X2, X3, (float*)d_out, nemb / 8);
}